// Round 2
// baseline (1315.022 us; speedup 1.0000x reference)
//
#include <hip/hip_runtime.h>

#define D        128
#define N_GRAPHS 64
#define N_CLS    16
#define GS_NB    32

// ---------------- CSR build ----------------

__global__ void k_deg(const int* __restrict__ dst, int* __restrict__ deg, int E) {
    int e = blockIdx.x * 256 + threadIdx.x;
    if (e < E) atomicAdd(&deg[dst[e]], 1);
}

__global__ void k_scan1(const int* __restrict__ deg, int* __restrict__ rowptr,
                        int* __restrict__ bsum, int N) {
    __shared__ int sh[1024];
    int t = threadIdx.x;
    int i = blockIdx.x * 1024 + t;
    int v = (i < N) ? deg[i] : 0;
    sh[t] = v;
    __syncthreads();
    for (int off = 1; off < 1024; off <<= 1) {
        int tmp = (t >= off) ? sh[t - off] : 0;
        __syncthreads();
        sh[t] += tmp;
        __syncthreads();
    }
    if (i < N) rowptr[i + 1] = sh[t];
    if (t == 1023) bsum[blockIdx.x] = sh[1023];
}

__global__ void k_scan2(const int* __restrict__ bsum, int* __restrict__ boff, int nch) {
    if (threadIdx.x == 0 && blockIdx.x == 0) {
        int run = 0;
        for (int j = 0; j < nch; j++) { boff[j] = run; run += bsum[j]; }
    }
}

__global__ void k_scan3(const int* __restrict__ deg, int* __restrict__ rowptr,
                        const int* __restrict__ boff, float* __restrict__ invdeg, int N) {
    int i = blockIdx.x * 256 + threadIdx.x;
    if (i < N) {
        rowptr[i + 1] += boff[i >> 10];
        int d = deg[i];
        invdeg[i] = 1.0f / (float)(d > 1 ? d : 1);
        if (i == 0) rowptr[0] = 0;
    }
}

__global__ void k_scatter(const int* __restrict__ src, const int* __restrict__ dst,
                          const int* __restrict__ rowptr, int* __restrict__ cursor,
                          int* __restrict__ csr, int E) {
    int e = blockIdx.x * 256 + threadIdx.x;
    if (e < E) {
        int d = dst[e];
        int p = atomicAdd(&cursor[d], 1);
        csr[rowptr[d] + p] = src[e];
    }
}

__global__ void k_hist(const int* __restrict__ gid, int* __restrict__ gcnt, int N) {
    __shared__ int lh[N_GRAPHS];
    int t = threadIdx.x;
    if (t < N_GRAPHS) lh[t] = 0;
    __syncthreads();
    int i = blockIdx.x * 256 + t;
    if (i < N) atomicAdd(&lh[gid[i]], 1);
    __syncthreads();
    if (t < N_GRAPHS && lh[t] > 0) atomicAdd(&gcnt[t], lh[t]);
}

// ---------------- neighbor mean aggregation (gather over CSR) ----------------
// one block (128 threads) per destination node; lanes = feature columns.
// edge loop unrolled x4 with independent accumulators for MLP; csr[e] loads
// are block-uniform -> scalar loads.

__global__ void k_agg(const float* __restrict__ feat, const int* __restrict__ rowptr,
                      const int* __restrict__ csr, const float* __restrict__ invdeg,
                      float* __restrict__ out) {
    int n = blockIdx.x;
    int c = threadIdx.x;
    int r0 = rowptr[n], r1 = rowptr[n + 1];
    float a0 = 0.f, a1 = 0.f, a2 = 0.f, a3 = 0.f;
    int e = r0;
    for (; e + 4 <= r1; e += 4) {
        int s0 = csr[e + 0];
        int s1 = csr[e + 1];
        int s2 = csr[e + 2];
        int s3 = csr[e + 3];
        a0 += feat[(size_t)s0 * D + c];
        a1 += feat[(size_t)s1 * D + c];
        a2 += feat[(size_t)s2 * D + c];
        a3 += feat[(size_t)s3 * D + c];
    }
    for (; e < r1; e++) a0 += feat[(size_t)csr[e] * D + c];
    out[(size_t)n * D + c] = ((a0 + a1) + (a2 + a3)) * invdeg[n];
}

// ---------------- layer-1 fused dual-matmul + bias + relu ----------------
// x1[n][:] = relu(h[n]@W1s + neigh[n]@W1n + b1).
// 2 threads per node: half = t>>7 (wave-uniform) covers cols [half*64, half*64+64).
// acc[64] per thread -> no spill. A staged in LDS (stride 17: conflict-free).
// W row addresses wave-uniform -> scalar broadcast loads.

__global__ __launch_bounds__(256) void k_mm1(
    const float* __restrict__ h, const float* __restrict__ nb,
    const float* __restrict__ Ws, const float* __restrict__ Wn,
    const float* __restrict__ b, float* __restrict__ x1, int N) {
    __shared__ float ht[128][17];
    __shared__ float gt[128][17];
    int t = threadIdx.x;
    int lane = t & 127;   // node within block
    int half = t >> 7;    // 0/1, wave-uniform
    int n0 = blockIdx.x * 128;
    int n = n0 + lane;
    bool valid = n < N;

    float acc[64];
#pragma unroll
    for (int c = 0; c < 64; c++) acc[c] = 0.f;

    for (int k0 = 0; k0 < D; k0 += 16) {
        __syncthreads();
        // cooperative stage: 1024 float4 chunks total (2 mats x 128 rows x 4 quads)
#pragma unroll
        for (int m = 0; m < 4; m++) {
            int linear = m * 256 + t;            // [0,1024)
            int mat    = linear >> 9;            // 0: h, 1: nb
            int rc     = linear & 511;
            int row    = rc >> 2;
            int q      = rc & 3;
            int nn = n0 + row;
            if (nn < N) {
                const float* srcp = (mat ? nb : h) + (size_t)nn * D + k0 + 4 * q;
                float4 v = *(const float4*)srcp;
                float* dp = (mat ? &gt[row][4 * q] : &ht[row][4 * q]);
                dp[0] = v.x; dp[1] = v.y; dp[2] = v.z; dp[3] = v.w;
            }
        }
        __syncthreads();
#pragma unroll
        for (int kk = 0; kk < 16; kk++) {
            float a1 = ht[lane][kk];
            float a2 = gt[lane][kk];
            const float* __restrict__ wsr = Ws + (k0 + kk) * D + half * 64;
            const float* __restrict__ wnr = Wn + (k0 + kk) * D + half * 64;
#pragma unroll
            for (int c = 0; c < 64; c++) {
                acc[c] = fmaf(a1, wsr[c], acc[c]);
                acc[c] = fmaf(a2, wnr[c], acc[c]);
            }
        }
    }
    if (valid) {
        float* __restrict__ orow = x1 + (size_t)n * D + half * 64;
        const float* __restrict__ bp = b + half * 64;
#pragma unroll
        for (int c4 = 0; c4 < 64; c4 += 4) {
            float4 v;
            v.x = fmaxf(acc[c4 + 0] + bp[c4 + 0], 0.f);
            v.y = fmaxf(acc[c4 + 1] + bp[c4 + 1], 0.f);
            v.z = fmaxf(acc[c4 + 2] + bp[c4 + 2], 0.f);
            v.w = fmaxf(acc[c4 + 3] + bp[c4 + 3], 0.f);
            *(float4*)(orow + c4) = v;
        }
    }
}

// ---------------- per-graph sums (coalesced; graph_ids sorted) ----------------
// S1[g] = sum_{n in g} x1[n];  S2[g] = sum_{n in g} neigh2[n]

__global__ void k_gsum(const float* __restrict__ x1, const float* __restrict__ n2,
                       const int* __restrict__ gid, float* __restrict__ S1,
                       float* __restrict__ S2, int N) {
    int c = threadIdx.x;  // 128
    int base = blockIdx.x * GS_NB;
    float a1 = 0.f, a2 = 0.f;
    int cur = -1;
    for (int i = 0; i < GS_NB; i++) {
        int n = base + i;
        if (n >= N) break;
        int g = gid[n];
        if (g != cur) {
            if (cur >= 0) {
                atomicAdd(&S1[cur * D + c], a1);
                atomicAdd(&S2[cur * D + c], a2);
            }
            a1 = 0.f; a2 = 0.f; cur = g;
        }
        a1 += x1[(size_t)n * D + c];
        a2 += n2[(size_t)n * D + c];
    }
    if (cur >= 0) {
        atomicAdd(&S1[cur * D + c], a1);
        atomicAdd(&S2[cur * D + c], a2);
    }
}

// ---------------- final: hg = (S1@W2s + S2@W2n)/cnt + b2 ; out = hg@Wc + bc ----

__global__ void k_final(const float* __restrict__ S1, const float* __restrict__ S2,
                        const int* __restrict__ gcnt, const float* __restrict__ W2s,
                        const float* __restrict__ W2n, const float* __restrict__ b2,
                        const float* __restrict__ Wc, const float* __restrict__ bc,
                        float* __restrict__ out) {
    __shared__ float s1[D], s2[D], hg[D];
    int g = blockIdx.x, c = threadIdx.x;
    s1[c] = S1[g * D + c];
    s2[c] = S2[g * D + c];
    __syncthreads();
    float acc = 0.f;
#pragma unroll 8
    for (int k = 0; k < D; k++) {
        acc = fmaf(s1[k], W2s[k * D + c], acc);
        acc = fmaf(s2[k], W2n[k * D + c], acc);
    }
    int cnt = gcnt[g];
    hg[c] = (cnt > 0) ? (acc / (float)cnt + b2[c]) : 0.f;
    __syncthreads();
    if (c < N_CLS) {
        float o = bc[c];
        for (int k = 0; k < D; k++) o = fmaf(hg[k], Wc[k * N_CLS + c], o);
        out[g * N_CLS + c] = o;
    }
}

// ---------------- launch ----------------

extern "C" void kernel_launch(void* const* d_in, const int* in_sizes, int n_in,
                              void* d_out, int out_size, void* d_ws, size_t ws_size,
                              hipStream_t stream) {
    const float* h   = (const float*)d_in[0];
    const int*   src = (const int*)d_in[1];
    const int*   dst = (const int*)d_in[2];
    const int*   gid = (const int*)d_in[3];
    const float* W1s = (const float*)d_in[5];
    const float* W1n = (const float*)d_in[6];
    const float* b1  = (const float*)d_in[7];
    const float* W2s = (const float*)d_in[8];
    const float* W2n = (const float*)d_in[9];
    const float* b2  = (const float*)d_in[10];
    const float* Wc  = (const float*)d_in[11];
    const float* bc  = (const float*)d_in[12];
    float* out = (float*)d_out;

    const int N = in_sizes[0] / D;  // 100000
    const int E = in_sizes[1];      // 1600000

    char* w = (char*)d_ws;
    size_t off = 0;
    auto alloc = [&](size_t elems) -> void* {
        void* p = w + off;
        off += elems * 4;
        return p;
    };
    // zero-initialized region first (one memset)
    float* S1     = (float*)alloc((size_t)N_GRAPHS * D);
    float* S2     = (float*)alloc((size_t)N_GRAPHS * D);
    int*   deg    = (int*)alloc(N);
    int*   cursor = (int*)alloc(N);
    int*   gcnt   = (int*)alloc(64);
    size_t zero_bytes = off;
    int*   rowptr = (int*)alloc(N + 4);     // keep 16B alignment for later buffers
    float* invdeg = (float*)alloc(N);
    int*   bsum   = (int*)alloc(128);
    int*   boff   = (int*)alloc(128);
    int*   csr    = (int*)alloc(E);
    float* neigh  = (float*)alloc((size_t)N * D);   // layer-1 agg; reused as neigh2
    float* x1     = (float*)alloc((size_t)N * D);
    (void)ws_size;

    hipMemsetAsync(d_ws, 0, zero_bytes, stream);

    int eb  = (E + 255) / 256;
    int nbk = (N + 255) / 256;
    int nch = (N + 1023) / 1024;

    k_deg<<<eb, 256, 0, stream>>>(dst, deg, E);
    k_scan1<<<nch, 1024, 0, stream>>>(deg, rowptr, bsum, N);
    k_scan2<<<1, 64, 0, stream>>>(bsum, boff, nch);
    k_scan3<<<nbk, 256, 0, stream>>>(deg, rowptr, boff, invdeg, N);
    k_scatter<<<eb, 256, 0, stream>>>(src, dst, rowptr, cursor, csr, E);
    k_hist<<<nbk, 256, 0, stream>>>(gid, gcnt, N);
    k_agg<<<N, 128, 0, stream>>>(h, rowptr, csr, invdeg, neigh);
    k_mm1<<<(N + 127) / 128, 256, 0, stream>>>(h, neigh, W1s, W1n, b1, x1, N);
    k_agg<<<N, 128, 0, stream>>>(x1, rowptr, csr, invdeg, neigh);  // neigh2 (reuse)
    k_gsum<<<(N + GS_NB - 1) / GS_NB, 128, 0, stream>>>(x1, neigh, gid, S1, S2, N);
    k_final<<<N_GRAPHS, 128, 0, stream>>>(S1, S2, gcnt, W2s, W2n, b2, Wc, bc, out);
}

// Round 3
// 699.974 us; speedup vs baseline: 1.8787x; 1.8787x over previous
//
#include <hip/hip_runtime.h>

#define D        128
#define N_GRAPHS 64
#define N_CLS    16
#define BK       32
#define GS_ROWS  128

// ---------------- CSR build ----------------

__global__ void k_deg(const int* __restrict__ dst, int* __restrict__ deg, int E) {
    int e = blockIdx.x * 256 + threadIdx.x;
    if (e < E) atomicAdd(&deg[dst[e]], 1);
}

__global__ void k_scan1(const int* __restrict__ deg, int* __restrict__ rowptr,
                        int* __restrict__ bsum, int N) {
    __shared__ int sh[1024];
    int t = threadIdx.x;
    int i = blockIdx.x * 1024 + t;
    int v = (i < N) ? deg[i] : 0;
    sh[t] = v;
    __syncthreads();
    for (int off = 1; off < 1024; off <<= 1) {
        int tmp = (t >= off) ? sh[t - off] : 0;
        __syncthreads();
        sh[t] += tmp;
        __syncthreads();
    }
    if (i < N) rowptr[i + 1] = sh[t];
    if (t == 1023) bsum[blockIdx.x] = sh[1023];
}

__global__ void k_scan2(const int* __restrict__ bsum, int* __restrict__ boff, int nch) {
    if (threadIdx.x == 0 && blockIdx.x == 0) {
        int run = 0;
        for (int j = 0; j < nch; j++) { boff[j] = run; run += bsum[j]; }
    }
}

__global__ void k_scan3(const int* __restrict__ deg, int* __restrict__ rowptr,
                        const int* __restrict__ boff, float* __restrict__ invdeg, int N) {
    int i = blockIdx.x * 256 + threadIdx.x;
    if (i < N) {
        rowptr[i + 1] += boff[i >> 10];
        int d = deg[i];
        invdeg[i] = 1.0f / (float)(d > 1 ? d : 1);
        if (i == 0) rowptr[0] = 0;
    }
}

__global__ void k_scatter(const int* __restrict__ src, const int* __restrict__ dst,
                          const int* __restrict__ rowptr, int* __restrict__ cursor,
                          int* __restrict__ csr, int E) {
    int e = blockIdx.x * 256 + threadIdx.x;
    if (e < E) {
        int d = dst[e];
        int p = atomicAdd(&cursor[d], 1);
        csr[rowptr[d] + p] = src[e];
    }
}

__global__ void k_hist(const int* __restrict__ gid, int* __restrict__ gcnt, int N) {
    __shared__ int lh[N_GRAPHS];
    int t = threadIdx.x;
    if (t < N_GRAPHS) lh[t] = 0;
    __syncthreads();
    int i = blockIdx.x * 256 + t;
    if (i < N) atomicAdd(&lh[gid[i]], 1);
    __syncthreads();
    if (t < N_GRAPHS && lh[t] > 0) atomicAdd(&gcnt[t], lh[t]);
}

// ---------------- neighbor mean aggregation: wave per node ----------------
// lane = (half, col-quad): lanes 0-31 do edges e, e+2,...; lanes 32-63 do e+1, e+3...
// Each float4 gather instr moves 2 full feature rows (1 KB). shfl_xor(32) combines.

__global__ __launch_bounds__(256) void k_agg(
    const float* __restrict__ feat, const int* __restrict__ rowptr,
    const int* __restrict__ csr, const float* __restrict__ invdeg,
    float* __restrict__ out, int N) {
    int lane = threadIdx.x & 63;
    int n = blockIdx.x * 4 + (threadIdx.x >> 6);
    if (n >= N) return;
    int r0 = rowptr[n], r1 = rowptr[n + 1];
    int half = lane >> 5;
    int c4 = (lane & 31) * 4;

    float ax = 0.f, ay = 0.f, az = 0.f, aw = 0.f;
    float bx = 0.f, by = 0.f, bz = 0.f, bw = 0.f;
    int e = r0 + half;
    for (; e + 2 < r1; e += 4) {   // process e and e+2 (per half)
        int s0 = csr[e];
        int s1 = csr[e + 2];
        float4 v0 = *(const float4*)(feat + (size_t)s0 * D + c4);
        float4 v1 = *(const float4*)(feat + (size_t)s1 * D + c4);
        ax += v0.x; ay += v0.y; az += v0.z; aw += v0.w;
        bx += v1.x; by += v1.y; bz += v1.z; bw += v1.w;
    }
    for (; e < r1; e += 2) {
        int s = csr[e];
        float4 v = *(const float4*)(feat + (size_t)s * D + c4);
        ax += v.x; ay += v.y; az += v.z; aw += v.w;
    }
    ax += bx; ay += by; az += bz; aw += bw;
    ax += __shfl_xor(ax, 32);
    ay += __shfl_xor(ay, 32);
    az += __shfl_xor(az, 32);
    aw += __shfl_xor(aw, 32);
    if (lane < 32) {
        float id = invdeg[n];
        float4 o;
        o.x = ax * id; o.y = ay * id; o.z = az * id; o.w = aw * id;
        *(float4*)(out + (size_t)n * D + c4) = o;
    }
}

// ---------------- layer-1: tiled GEMM, K-concat ----------------
// x1[128-row tile][128 cols] = relu([h|nb] @ [Ws;Wn] + b), K=256 in 8 chunks of 32.
// 256 threads, micro-tile 8 rows x (4+4) cols. Both A and W staged in LDS.

__global__ __launch_bounds__(256, 2) void k_mm1(
    const float* __restrict__ h, const float* __restrict__ nb,
    const float* __restrict__ Ws, const float* __restrict__ Wn,
    const float* __restrict__ b, float* __restrict__ x1, int N) {
    __shared__ float As[128][33];
    __shared__ float Wt[BK][132];
    int t  = threadIdx.x;
    int tx = t & 15;          // col group: cols tx*4..+3 and 64+tx*4..+3
    int ty = t >> 4;          // row group: rows ty*8..+7
    int n0 = blockIdx.x * 128;

    float4 acc[8][2];
#pragma unroll
    for (int i = 0; i < 8; i++) {
        acc[i][0] = make_float4(0.f, 0.f, 0.f, 0.f);
        acc[i][1] = make_float4(0.f, 0.f, 0.f, 0.f);
    }

#pragma unroll 1
    for (int kc = 0; kc < 8; kc++) {
        int k0 = kc * BK;
        const float* __restrict__ A = (k0 < 128) ? h : nb;
        const float* __restrict__ W = (k0 < 128) ? Ws : Wn;
        int ka = k0 & 127;
        __syncthreads();
        // stage A: 128 rows x 32 k = 1024 float4, 4/thread
#pragma unroll
        for (int i = 0; i < 4; i++) {
            int linear = i * 256 + t;
            int row = linear >> 3;
            int kq  = linear & 7;
            int nn = n0 + row;
            if (nn < N) {
                float4 v = *(const float4*)(A + (size_t)nn * D + ka + 4 * kq);
                *(float4*)&As[row][4 * kq] = v;
            }
        }
        // stage W: 32 k-rows x 128 cols = 1024 float4, 4/thread
#pragma unroll
        for (int i = 0; i < 4; i++) {
            int linear = i * 256 + t;
            int row = linear >> 5;
            int cq  = linear & 31;
            float4 v = *(const float4*)(W + (size_t)(ka + row) * D + 4 * cq);
            *(float4*)&Wt[row][4 * cq] = v;
        }
        __syncthreads();
#pragma unroll
        for (int kk = 0; kk < BK; kk++) {
            float a[8];
#pragma unroll
            for (int i = 0; i < 8; i++) a[i] = As[ty * 8 + i][kk];
            float4 w0 = *(float4*)&Wt[kk][tx * 4];
            float4 w1 = *(float4*)&Wt[kk][64 + tx * 4];
#pragma unroll
            for (int i = 0; i < 8; i++) {
                acc[i][0].x = fmaf(a[i], w0.x, acc[i][0].x);
                acc[i][0].y = fmaf(a[i], w0.y, acc[i][0].y);
                acc[i][0].z = fmaf(a[i], w0.z, acc[i][0].z);
                acc[i][0].w = fmaf(a[i], w0.w, acc[i][0].w);
                acc[i][1].x = fmaf(a[i], w1.x, acc[i][1].x);
                acc[i][1].y = fmaf(a[i], w1.y, acc[i][1].y);
                acc[i][1].z = fmaf(a[i], w1.z, acc[i][1].z);
                acc[i][1].w = fmaf(a[i], w1.w, acc[i][1].w);
            }
        }
    }
    // epilogue: bias + relu
    float4 b0 = *(const float4*)(b + tx * 4);
    float4 b1 = *(const float4*)(b + 64 + tx * 4);
#pragma unroll
    for (int i = 0; i < 8; i++) {
        int n = n0 + ty * 8 + i;
        if (n < N) {
            float4 v0, v1;
            v0.x = fmaxf(acc[i][0].x + b0.x, 0.f);
            v0.y = fmaxf(acc[i][0].y + b0.y, 0.f);
            v0.z = fmaxf(acc[i][0].z + b0.z, 0.f);
            v0.w = fmaxf(acc[i][0].w + b0.w, 0.f);
            v1.x = fmaxf(acc[i][1].x + b1.x, 0.f);
            v1.y = fmaxf(acc[i][1].y + b1.y, 0.f);
            v1.z = fmaxf(acc[i][1].z + b1.z, 0.f);
            v1.w = fmaxf(acc[i][1].w + b1.w, 0.f);
            *(float4*)(x1 + (size_t)n * D + tx * 4) = v0;
            *(float4*)(x1 + (size_t)n * D + 64 + tx * 4) = v1;
        }
    }
}

// ---------------- per-graph sums (coalesced float4; graph_ids sorted) -------
// 128 threads = 32 col-quads x 4 row-lanes; each row-lane walks its rows,
// register-accumulates, flushes on graph change.

__global__ __launch_bounds__(128) void k_gsum(
    const float* __restrict__ x1, const float* __restrict__ n2,
    const int* __restrict__ gid, float* __restrict__ S1,
    float* __restrict__ S2, int N) {
    int t = threadIdx.x;
    int c4 = (t & 31) * 4;
    int rl = t >> 5;
    int base = blockIdx.x * GS_ROWS;
    float a1x = 0.f, a1y = 0.f, a1z = 0.f, a1w = 0.f;
    float a2x = 0.f, a2y = 0.f, a2z = 0.f, a2w = 0.f;
    int cur = -1;
    for (int j = rl; j < GS_ROWS; j += 4) {
        int n = base + j;
        if (n >= N) break;
        int g = gid[n];
        if (g != cur) {
            if (cur >= 0) {
                atomicAdd(&S1[cur * D + c4 + 0], a1x);
                atomicAdd(&S1[cur * D + c4 + 1], a1y);
                atomicAdd(&S1[cur * D + c4 + 2], a1z);
                atomicAdd(&S1[cur * D + c4 + 3], a1w);
                atomicAdd(&S2[cur * D + c4 + 0], a2x);
                atomicAdd(&S2[cur * D + c4 + 1], a2y);
                atomicAdd(&S2[cur * D + c4 + 2], a2z);
                atomicAdd(&S2[cur * D + c4 + 3], a2w);
            }
            a1x = a1y = a1z = a1w = 0.f;
            a2x = a2y = a2z = a2w = 0.f;
            cur = g;
        }
        float4 v1 = *(const float4*)(x1 + (size_t)n * D + c4);
        float4 v2 = *(const float4*)(n2 + (size_t)n * D + c4);
        a1x += v1.x; a1y += v1.y; a1z += v1.z; a1w += v1.w;
        a2x += v2.x; a2y += v2.y; a2z += v2.z; a2w += v2.w;
    }
    if (cur >= 0) {
        atomicAdd(&S1[cur * D + c4 + 0], a1x);
        atomicAdd(&S1[cur * D + c4 + 1], a1y);
        atomicAdd(&S1[cur * D + c4 + 2], a1z);
        atomicAdd(&S1[cur * D + c4 + 3], a1w);
        atomicAdd(&S2[cur * D + c4 + 0], a2x);
        atomicAdd(&S2[cur * D + c4 + 1], a2y);
        atomicAdd(&S2[cur * D + c4 + 2], a2z);
        atomicAdd(&S2[cur * D + c4 + 3], a2w);
    }
}

// ---------------- final: hg = (S1@W2s + S2@W2n)/cnt + b2 ; out = hg@Wc + bc ----

__global__ void k_final(const float* __restrict__ S1, const float* __restrict__ S2,
                        const int* __restrict__ gcnt, const float* __restrict__ W2s,
                        const float* __restrict__ W2n, const float* __restrict__ b2,
                        const float* __restrict__ Wc, const float* __restrict__ bc,
                        float* __restrict__ out) {
    __shared__ float s1[D], s2[D], hg[D];
    int g = blockIdx.x, c = threadIdx.x;
    s1[c] = S1[g * D + c];
    s2[c] = S2[g * D + c];
    __syncthreads();
    float acc = 0.f;
#pragma unroll 8
    for (int k = 0; k < D; k++) {
        acc = fmaf(s1[k], W2s[k * D + c], acc);
        acc = fmaf(s2[k], W2n[k * D + c], acc);
    }
    int cnt = gcnt[g];
    hg[c] = (cnt > 0) ? (acc / (float)cnt + b2[c]) : 0.f;
    __syncthreads();
    if (c < N_CLS) {
        float o = bc[c];
        for (int k = 0; k < D; k++) o = fmaf(hg[k], Wc[k * N_CLS + c], o);
        out[g * N_CLS + c] = o;
    }
}

// ---------------- launch ----------------

extern "C" void kernel_launch(void* const* d_in, const int* in_sizes, int n_in,
                              void* d_out, int out_size, void* d_ws, size_t ws_size,
                              hipStream_t stream) {
    const float* h   = (const float*)d_in[0];
    const int*   src = (const int*)d_in[1];
    const int*   dst = (const int*)d_in[2];
    const int*   gid = (const int*)d_in[3];
    const float* W1s = (const float*)d_in[5];
    const float* W1n = (const float*)d_in[6];
    const float* b1  = (const float*)d_in[7];
    const float* W2s = (const float*)d_in[8];
    const float* W2n = (const float*)d_in[9];
    const float* b2  = (const float*)d_in[10];
    const float* Wc  = (const float*)d_in[11];
    const float* bc  = (const float*)d_in[12];
    float* out = (float*)d_out;

    const int N = in_sizes[0] / D;  // 100000
    const int E = in_sizes[1];      // 1600000

    char* w = (char*)d_ws;
    size_t off = 0;
    auto alloc = [&](size_t elems) -> void* {
        void* p = w + off;
        off += elems * 4;
        return p;
    };
    // zero-initialized region first (one memset)
    float* S1     = (float*)alloc((size_t)N_GRAPHS * D);
    float* S2     = (float*)alloc((size_t)N_GRAPHS * D);
    int*   deg    = (int*)alloc(N);
    int*   cursor = (int*)alloc(N);
    int*   gcnt   = (int*)alloc(64);
    size_t zero_bytes = off;
    int*   rowptr = (int*)alloc(N + 4);     // keep 16B alignment for later buffers
    float* invdeg = (float*)alloc(N);
    int*   bsum   = (int*)alloc(128);
    int*   boff   = (int*)alloc(128);
    int*   csr    = (int*)alloc(E);
    float* neigh  = (float*)alloc((size_t)N * D);   // layer-1 agg; reused as neigh2
    float* x1     = (float*)alloc((size_t)N * D);
    (void)ws_size;

    hipMemsetAsync(d_ws, 0, zero_bytes, stream);

    int eb  = (E + 255) / 256;
    int nbk = (N + 255) / 256;
    int nch = (N + 1023) / 1024;

    k_deg<<<eb, 256, 0, stream>>>(dst, deg, E);
    k_scan1<<<nch, 1024, 0, stream>>>(deg, rowptr, bsum, N);
    k_scan2<<<1, 64, 0, stream>>>(bsum, boff, nch);
    k_scan3<<<nbk, 256, 0, stream>>>(deg, rowptr, boff, invdeg, N);
    k_scatter<<<eb, 256, 0, stream>>>(src, dst, rowptr, cursor, csr, E);
    k_hist<<<nbk, 256, 0, stream>>>(gid, gcnt, N);
    k_agg<<<(N + 3) / 4, 256, 0, stream>>>(h, rowptr, csr, invdeg, neigh, N);
    k_mm1<<<(N + 127) / 128, 256, 0, stream>>>(h, neigh, W1s, W1n, b1, x1, N);
    k_agg<<<(N + 3) / 4, 256, 0, stream>>>(x1, rowptr, csr, invdeg, neigh, N);
    k_gsum<<<(N + GS_ROWS - 1) / GS_ROWS, 128, 0, stream>>>(x1, neigh, gid, S1, S2, N);
    k_final<<<N_GRAPHS, 128, 0, stream>>>(S1, S2, gcnt, W2s, W2n, b2, Wc, bc, out);
}

// Round 5
// 682.311 us; speedup vs baseline: 1.9273x; 1.0259x over previous
//
#include <hip/hip_runtime.h>

#define D        128
#define N_GRAPHS 64
#define N_CLS    16
#define BK       32
#define GS_ROWS  128

typedef unsigned int  uint;
typedef unsigned short ushort;

__device__ inline ushort f2b(float f) {   // f32 -> bf16 RNE
    uint u = __float_as_uint(f);
    u += 0x7fffu + ((u >> 16) & 1u);
    return (ushort)(u >> 16);
}

// ---------------- CSR build ----------------

__global__ void k_deg(const int* __restrict__ dst, int* __restrict__ deg, int E) {
    int e = blockIdx.x * 256 + threadIdx.x;
    if (e < E) atomicAdd(&deg[dst[e]], 1);
}

__global__ void k_scan1(const int* __restrict__ deg, int* __restrict__ rowptr,
                        int* __restrict__ bsum, int N) {
    __shared__ int sh[1024];
    int t = threadIdx.x;
    int i = blockIdx.x * 1024 + t;
    int v = (i < N) ? deg[i] : 0;
    sh[t] = v;
    __syncthreads();
    for (int off = 1; off < 1024; off <<= 1) {
        int tmp = (t >= off) ? sh[t - off] : 0;
        __syncthreads();
        sh[t] += tmp;
        __syncthreads();
    }
    if (i < N) rowptr[i + 1] = sh[t];
    if (t == 1023) bsum[blockIdx.x] = sh[1023];
}

__global__ void k_scan2(const int* __restrict__ bsum, int* __restrict__ boff, int nch) {
    if (threadIdx.x == 0 && blockIdx.x == 0) {
        int run = 0;
        for (int j = 0; j < nch; j++) { boff[j] = run; run += bsum[j]; }
    }
}

__global__ void k_scan3(const int* __restrict__ deg, int* __restrict__ rowptr,
                        const int* __restrict__ boff, float* __restrict__ invdeg, int N) {
    int i = blockIdx.x * 256 + threadIdx.x;
    if (i < N) {
        rowptr[i + 1] += boff[i >> 10];
        int d = deg[i];
        invdeg[i] = 1.0f / (float)(d > 1 ? d : 1);
        if (i == 0) rowptr[0] = 0;
    }
}

__global__ void k_scatter(const int* __restrict__ src, const int* __restrict__ dst,
                          const int* __restrict__ rowptr, int* __restrict__ cursor,
                          int* __restrict__ csr, int E) {
    int e = blockIdx.x * 256 + threadIdx.x;
    if (e < E) {
        int d = dst[e];
        int p = atomicAdd(&cursor[d], 1);
        csr[rowptr[d] + p] = src[e];
    }
}

__global__ void k_hist(const int* __restrict__ gid, int* __restrict__ gcnt, int N) {
    __shared__ int lh[N_GRAPHS];
    int t = threadIdx.x;
    if (t < N_GRAPHS) lh[t] = 0;
    __syncthreads();
    int i = blockIdx.x * 256 + t;
    if (i < N) atomicAdd(&lh[gid[i]], 1);
    __syncthreads();
    if (t < N_GRAPHS && lh[t] > 0) atomicAdd(&gcnt[t], lh[t]);
}

// ---------------- f32 -> bf16 cast (vectorized) ----------------

__global__ void k_cast(const float* __restrict__ x, ushort* __restrict__ y, int total4) {
    int i = blockIdx.x * 256 + threadIdx.x;
    if (i < total4) {
        float4 v = ((const float4*)x)[i];
        ushort4 o;
        o.x = f2b(v.x); o.y = f2b(v.y); o.z = f2b(v.z); o.w = f2b(v.w);
        ((ushort4*)y)[i] = o;
    }
}

// ---------------- bf16 neighbor-mean gather: wave per node ----------------
// lane = (edge-quad ej, col-group cg of 8 cols). Each uint4 load = 8 bf16 cols;
// 4 edges in flight per wave per iter, x2 unrolled. f32 accumulate;
// shfl_xor(16,32) combines edge-quads; ej==0 lanes write the f32 row.

__global__ __launch_bounds__(256) void k_aggb(
    const ushort* __restrict__ fb, const int* __restrict__ rowptr,
    const int* __restrict__ csr, const float* __restrict__ invdeg,
    float* __restrict__ out, int N) {
    int lane = threadIdx.x & 63;
    int n = blockIdx.x * 4 + (threadIdx.x >> 6);
    if (n >= N) return;
    int r0 = rowptr[n], r1 = rowptr[n + 1];
    int ej = lane >> 4;      // 0..3
    int cg = lane & 15;      // cols cg*8 .. cg*8+7

    float acc[8];
#pragma unroll
    for (int i = 0; i < 8; i++) acc[i] = 0.f;

    int e = r0 + ej;
    for (; e + 4 < r1; e += 8) {
        int s0 = csr[e];
        int s1 = csr[e + 4];
        uint4 v0 = *(const uint4*)(fb + (size_t)s0 * D + cg * 8);
        uint4 v1 = *(const uint4*)(fb + (size_t)s1 * D + cg * 8);
        acc[0] += __uint_as_float(v0.x << 16);
        acc[1] += __uint_as_float(v0.x & 0xffff0000u);
        acc[2] += __uint_as_float(v0.y << 16);
        acc[3] += __uint_as_float(v0.y & 0xffff0000u);
        acc[4] += __uint_as_float(v0.z << 16);
        acc[5] += __uint_as_float(v0.z & 0xffff0000u);
        acc[6] += __uint_as_float(v0.w << 16);
        acc[7] += __uint_as_float(v0.w & 0xffff0000u);
        acc[0] += __uint_as_float(v1.x << 16);
        acc[1] += __uint_as_float(v1.x & 0xffff0000u);
        acc[2] += __uint_as_float(v1.y << 16);
        acc[3] += __uint_as_float(v1.y & 0xffff0000u);
        acc[4] += __uint_as_float(v1.z << 16);
        acc[5] += __uint_as_float(v1.z & 0xffff0000u);
        acc[6] += __uint_as_float(v1.w << 16);
        acc[7] += __uint_as_float(v1.w & 0xffff0000u);
    }
    for (; e < r1; e += 4) {
        int s = csr[e];
        uint4 v = *(const uint4*)(fb + (size_t)s * D + cg * 8);
        acc[0] += __uint_as_float(v.x << 16);
        acc[1] += __uint_as_float(v.x & 0xffff0000u);
        acc[2] += __uint_as_float(v.y << 16);
        acc[3] += __uint_as_float(v.y & 0xffff0000u);
        acc[4] += __uint_as_float(v.z << 16);
        acc[5] += __uint_as_float(v.z & 0xffff0000u);
        acc[6] += __uint_as_float(v.w << 16);
        acc[7] += __uint_as_float(v.w & 0xffff0000u);
    }
#pragma unroll
    for (int i = 0; i < 8; i++) {
        acc[i] += __shfl_xor(acc[i], 16);
        acc[i] += __shfl_xor(acc[i], 32);
    }
    if (ej == 0) {
        float id = invdeg[n];
        float4 o0, o1;
        o0.x = acc[0] * id; o0.y = acc[1] * id; o0.z = acc[2] * id; o0.w = acc[3] * id;
        o1.x = acc[4] * id; o1.y = acc[5] * id; o1.z = acc[6] * id; o1.w = acc[7] * id;
        *(float4*)(out + (size_t)n * D + cg * 8)     = o0;
        *(float4*)(out + (size_t)n * D + cg * 8 + 4) = o1;
    }
}

// ---------------- layer-1: tiled GEMM, K-concat, transposed A-tile ----------
// x1b[128 rows][128 cols] = bf16(relu([h|nb] @ [Ws;Wn] + b)), K=256 in 8x32.
// As stored [k][row] (pad 140 -> rows 16B-aligned; reads: 2x b128 broadcast,
// conflict-free; staging writes 4-way, cheap). Output bf16 only.

__global__ __launch_bounds__(256, 3) void k_mm1(
    const float* __restrict__ h, const float* __restrict__ nb,
    const float* __restrict__ Ws, const float* __restrict__ Wn,
    const float* __restrict__ b, ushort* __restrict__ x1b, int N) {
    __shared__ float As[BK][140];
    __shared__ float Wt[BK][132];
    int t  = threadIdx.x;
    int tx = t & 15;          // col group: cols tx*4..+3 and 64+tx*4..+3
    int ty = t >> 4;          // row group: rows ty*8..+7
    int n0 = blockIdx.x * 128;

    float4 acc[8][2];
#pragma unroll
    for (int i = 0; i < 8; i++) {
        acc[i][0] = make_float4(0.f, 0.f, 0.f, 0.f);
        acc[i][1] = make_float4(0.f, 0.f, 0.f, 0.f);
    }

#pragma unroll 1
    for (int kc = 0; kc < 8; kc++) {
        int k0 = kc * BK;
        const float* __restrict__ A = (k0 < 128) ? h : nb;
        const float* __restrict__ W = (k0 < 128) ? Ws : Wn;
        int ka = k0 & 127;
        __syncthreads();
        // stage A transposed: 128 rows x 32 k
#pragma unroll
        for (int i = 0; i < 4; i++) {
            int linear = i * 256 + t;
            int row = linear >> 3;
            int kq  = linear & 7;
            int nn = n0 + row;
            float4 v = make_float4(0.f, 0.f, 0.f, 0.f);
            if (nn < N) v = *(const float4*)(A + (size_t)nn * D + ka + 4 * kq);
            As[4 * kq + 0][row] = v.x;
            As[4 * kq + 1][row] = v.y;
            As[4 * kq + 2][row] = v.z;
            As[4 * kq + 3][row] = v.w;
        }
        // stage W: 32 k-rows x 128 cols
#pragma unroll
        for (int i = 0; i < 4; i++) {
            int linear = i * 256 + t;
            int row = linear >> 5;
            int cq  = linear & 31;
            float4 v = *(const float4*)(W + (size_t)(ka + row) * D + 4 * cq);
            *(float4*)&Wt[row][4 * cq] = v;
        }
        __syncthreads();
#pragma unroll
        for (int kk = 0; kk < BK; kk++) {
            float4 a0 = *(float4*)&As[kk][ty * 8];
            float4 a1 = *(float4*)&As[kk][ty * 8 + 4];
            float4 w0 = *(float4*)&Wt[kk][tx * 4];
            float4 w1 = *(float4*)&Wt[kk][64 + tx * 4];
            float a[8] = {a0.x, a0.y, a0.z, a0.w, a1.x, a1.y, a1.z, a1.w};
#pragma unroll
            for (int i = 0; i < 8; i++) {
                acc[i][0].x = fmaf(a[i], w0.x, acc[i][0].x);
                acc[i][0].y = fmaf(a[i], w0.y, acc[i][0].y);
                acc[i][0].z = fmaf(a[i], w0.z, acc[i][0].z);
                acc[i][0].w = fmaf(a[i], w0.w, acc[i][0].w);
                acc[i][1].x = fmaf(a[i], w1.x, acc[i][1].x);
                acc[i][1].y = fmaf(a[i], w1.y, acc[i][1].y);
                acc[i][1].z = fmaf(a[i], w1.z, acc[i][1].z);
                acc[i][1].w = fmaf(a[i], w1.w, acc[i][1].w);
            }
        }
    }
    // epilogue: bias + relu, write bf16
    float4 b0 = *(const float4*)(b + tx * 4);
    float4 b1 = *(const float4*)(b + 64 + tx * 4);
#pragma unroll
    for (int i = 0; i < 8; i++) {
        int n = n0 + ty * 8 + i;
        if (n < N) {
            ushort4 p0, p1;
            p0.x = f2b(fmaxf(acc[i][0].x + b0.x, 0.f));
            p0.y = f2b(fmaxf(acc[i][0].y + b0.y, 0.f));
            p0.z = f2b(fmaxf(acc[i][0].z + b0.z, 0.f));
            p0.w = f2b(fmaxf(acc[i][0].w + b0.w, 0.f));
            p1.x = f2b(fmaxf(acc[i][1].x + b1.x, 0.f));
            p1.y = f2b(fmaxf(acc[i][1].y + b1.y, 0.f));
            p1.z = f2b(fmaxf(acc[i][1].z + b1.z, 0.f));
            p1.w = f2b(fmaxf(acc[i][1].w + b1.w, 0.f));
            *(ushort4*)(x1b + (size_t)n * D + tx * 4) = p0;
            *(ushort4*)(x1b + (size_t)n * D + 64 + tx * 4) = p1;
        }
    }
}

// ---------------- per-graph sums (graph_ids sorted) -------------------------
// S1 from bf16 x1b, S2 from f32 neigh2. 128 threads = 16 col-groups x 8 rows.

__global__ __launch_bounds__(128) void k_gsum(
    const ushort* __restrict__ x1b, const float* __restrict__ n2,
    const int* __restrict__ gid, float* __restrict__ S1,
    float* __restrict__ S2, int N) {
    int t = threadIdx.x;
    int cg = t & 15;       // cols cg*8 .. +7
    int rl = t >> 4;       // 0..7
    int base = blockIdx.x * GS_ROWS;
    float a1[8], a2[8];
#pragma unroll
    for (int i = 0; i < 8; i++) { a1[i] = 0.f; a2[i] = 0.f; }
    int cur = -1;
    for (int j = rl; j < GS_ROWS; j += 8) {
        int n = base + j;
        if (n >= N) break;
        int g = gid[n];
        if (g != cur) {
            if (cur >= 0) {
#pragma unroll
                for (int i = 0; i < 8; i++) {
                    atomicAdd(&S1[cur * D + cg * 8 + i], a1[i]);
                    atomicAdd(&S2[cur * D + cg * 8 + i], a2[i]);
                }
            }
#pragma unroll
            for (int i = 0; i < 8; i++) { a1[i] = 0.f; a2[i] = 0.f; }
            cur = g;
        }
        uint4 v = *(const uint4*)(x1b + (size_t)n * D + cg * 8);
        a1[0] += __uint_as_float(v.x << 16);
        a1[1] += __uint_as_float(v.x & 0xffff0000u);
        a1[2] += __uint_as_float(v.y << 16);
        a1[3] += __uint_as_float(v.y & 0xffff0000u);
        a1[4] += __uint_as_float(v.z << 16);
        a1[5] += __uint_as_float(v.z & 0xffff0000u);
        a1[6] += __uint_as_float(v.w << 16);
        a1[7] += __uint_as_float(v.w & 0xffff0000u);
        float4 w0 = *(const float4*)(n2 + (size_t)n * D + cg * 8);
        float4 w1 = *(const float4*)(n2 + (size_t)n * D + cg * 8 + 4);
        a2[0] += w0.x; a2[1] += w0.y; a2[2] += w0.z; a2[3] += w0.w;
        a2[4] += w1.x; a2[5] += w1.y; a2[6] += w1.z; a2[7] += w1.w;
    }
    if (cur >= 0) {
#pragma unroll
        for (int i = 0; i < 8; i++) {
            atomicAdd(&S1[cur * D + cg * 8 + i], a1[i]);
            atomicAdd(&S2[cur * D + cg * 8 + i], a2[i]);
        }
    }
}

// ---------------- final: hg = (S1@W2s + S2@W2n)/cnt + b2 ; out = hg@Wc + bc ----

__global__ void k_final(const float* __restrict__ S1, const float* __restrict__ S2,
                        const int* __restrict__ gcnt, const float* __restrict__ W2s,
                        const float* __restrict__ W2n, const float* __restrict__ b2,
                        const float* __restrict__ Wc, const float* __restrict__ bc,
                        float* __restrict__ out) {
    __shared__ float s1[D], s2[D], hg[D];
    int g = blockIdx.x, c = threadIdx.x;
    s1[c] = S1[g * D + c];
    s2[c] = S2[g * D + c];
    __syncthreads();
    float acc = 0.f;
#pragma unroll 8
    for (int k = 0; k < D; k++) {
        acc = fmaf(s1[k], W2s[k * D + c], acc);
        acc = fmaf(s2[k], W2n[k * D + c], acc);
    }
    int cnt = gcnt[g];
    hg[c] = (cnt > 0) ? (acc / (float)cnt + b2[c]) : 0.f;
    __syncthreads();
    if (c < N_CLS) {
        float o = bc[c];
        for (int k = 0; k < D; k++) o = fmaf(hg[k], Wc[k * N_CLS + c], o);
        out[g * N_CLS + c] = o;
    }
}

// ---------------- launch ----------------

extern "C" void kernel_launch(void* const* d_in, const int* in_sizes, int n_in,
                              void* d_out, int out_size, void* d_ws, size_t ws_size,
                              hipStream_t stream) {
    const float* h   = (const float*)d_in[0];
    const int*   src = (const int*)d_in[1];
    const int*   dst = (const int*)d_in[2];
    const int*   gid = (const int*)d_in[3];
    const float* W1s = (const float*)d_in[5];
    const float* W1n = (const float*)d_in[6];
    const float* b1  = (const float*)d_in[7];
    const float* W2s = (const float*)d_in[8];
    const float* W2n = (const float*)d_in[9];
    const float* b2  = (const float*)d_in[10];
    const float* Wc  = (const float*)d_in[11];
    const float* bc  = (const float*)d_in[12];
    float* out = (float*)d_out;

    const int N = in_sizes[0] / D;  // 100000
    const int E = in_sizes[1];      // 1600000

    char* w = (char*)d_ws;
    size_t off = 0;
    auto alloc = [&](size_t elems) -> void* {   // elems are 4-byte units
        void* p = w + off;
        off += elems * 4;
        return p;
    };
    // zero-initialized region first (one memset)
    float* S1     = (float*)alloc((size_t)N_GRAPHS * D);
    float* S2     = (float*)alloc((size_t)N_GRAPHS * D);
    int*   deg    = (int*)alloc(N);
    int*   cursor = (int*)alloc(N);
    int*   gcnt   = (int*)alloc(64);
    size_t zero_bytes = off;
    int*   rowptr = (int*)alloc(N + 4);
    float* invdeg = (float*)alloc(N);
    int*   bsum   = (int*)alloc(128);
    int*   boff   = (int*)alloc(128);
    int*   csr    = (int*)alloc(E);
    ushort* fb    = (ushort*)alloc((size_t)N * 64);   // bf16 [N,128]: h, then x1 (N*64 4B units = 256N bytes)
    float* neigh  = (float*)alloc((size_t)N * D);     // agg1 out; reused for agg2 out
    (void)ws_size;

    hipMemsetAsync(d_ws, 0, zero_bytes, stream);

    int eb  = (E + 255) / 256;
    int nbk = (N + 255) / 256;
    int nch = (N + 1023) / 1024;
    int t4  = N * 32;  // float4 count of a [N,128] f32 matrix

    k_cast<<<(t4 + 255) / 256, 256, 0, stream>>>(h, fb, t4);
    k_deg<<<eb, 256, 0, stream>>>(dst, deg, E);
    k_scan1<<<nch, 1024, 0, stream>>>(deg, rowptr, bsum, N);
    k_scan2<<<1, 64, 0, stream>>>(bsum, boff, nch);
    k_scan3<<<nbk, 256, 0, stream>>>(deg, rowptr, boff, invdeg, N);
    k_scatter<<<eb, 256, 0, stream>>>(src, dst, rowptr, cursor, csr, E);
    k_hist<<<nbk, 256, 0, stream>>>(gid, gcnt, N);
    k_aggb<<<(N + 3) / 4, 256, 0, stream>>>(fb, rowptr, csr, invdeg, neigh, N);
    k_mm1<<<(N + 127) / 128, 256, 0, stream>>>(h, neigh, W1s, W1n, b1, fb, N);
    k_aggb<<<(N + 3) / 4, 256, 0, stream>>>(fb, rowptr, csr, invdeg, neigh, N);
    k_gsum<<<(N + GS_ROWS - 1) / GS_ROWS, 128, 0, stream>>>(fb, neigh, gid, S1, S2, N);
    k_final<<<N_GRAPHS, 128, 0, stream>>>(S1, S2, gcnt, W2s, W2n, b2, Wc, bc, out);
}

// Round 6
// 593.067 us; speedup vs baseline: 2.2173x; 1.1505x over previous
//
#include <hip/hip_runtime.h>

#define D        128
#define N_GRAPHS 64
#define N_CLS    16
#define GS_ROWS  128
#define LDA      40   // LDS row stride in bf16 elems (80 B: 16B-aligned, 2-way banks = free)

typedef unsigned int  uint;
typedef unsigned short ushort;
typedef __attribute__((ext_vector_type(8))) short short8;
typedef __attribute__((ext_vector_type(4))) float f32x4;

__device__ inline ushort f2b(float f) {   // f32 -> bf16 RNE
    uint u = __float_as_uint(f);
    u += 0x7fffu + ((u >> 16) & 1u);
    return (ushort)(u >> 16);
}

// ---------------- CSR build ----------------

__global__ void k_deg(const int* __restrict__ dst, int* __restrict__ deg, int E) {
    int e = blockIdx.x * 256 + threadIdx.x;
    if (e < E) atomicAdd(&deg[dst[e]], 1);
}

__global__ void k_scan1(const int* __restrict__ deg, int* __restrict__ rowptr,
                        int* __restrict__ bsum, int N) {
    __shared__ int sh[1024];
    int t = threadIdx.x;
    int i = blockIdx.x * 1024 + t;
    int v = (i < N) ? deg[i] : 0;
    sh[t] = v;
    __syncthreads();
    for (int off = 1; off < 1024; off <<= 1) {
        int tmp = (t >= off) ? sh[t - off] : 0;
        __syncthreads();
        sh[t] += tmp;
        __syncthreads();
    }
    if (i < N) rowptr[i + 1] = sh[t];
    if (t == 1023) bsum[blockIdx.x] = sh[1023];
}

__global__ void k_scan2(const int* __restrict__ bsum, int* __restrict__ boff, int nch) {
    if (threadIdx.x == 0 && blockIdx.x == 0) {
        int run = 0;
        for (int j = 0; j < nch; j++) { boff[j] = run; run += bsum[j]; }
    }
}

__global__ void k_scan3(const int* __restrict__ deg, int* __restrict__ rowptr,
                        const int* __restrict__ boff, float* __restrict__ invdeg, int N) {
    int i = blockIdx.x * 256 + threadIdx.x;
    if (i < N) {
        rowptr[i + 1] += boff[i >> 10];
        int d = deg[i];
        invdeg[i] = 1.0f / (float)(d > 1 ? d : 1);
        if (i == 0) rowptr[0] = 0;
    }
}

__global__ void k_scatter(const int* __restrict__ src, const int* __restrict__ dst,
                          const int* __restrict__ rowptr, int* __restrict__ cursor,
                          int* __restrict__ csr, int E) {
    int e = blockIdx.x * 256 + threadIdx.x;
    if (e < E) {
        int d = dst[e];
        int p = atomicAdd(&cursor[d], 1);
        csr[rowptr[d] + p] = src[e];
    }
}

__global__ void k_hist(const int* __restrict__ gid, int* __restrict__ gcnt, int N) {
    __shared__ int lh[N_GRAPHS];
    int t = threadIdx.x;
    if (t < N_GRAPHS) lh[t] = 0;
    __syncthreads();
    int i = blockIdx.x * 256 + t;
    if (i < N) atomicAdd(&lh[gid[i]], 1);
    __syncthreads();
    if (t < N_GRAPHS && lh[t] > 0) atomicAdd(&gcnt[t], lh[t]);
}

// ---------------- casts ----------------

__global__ void k_cast(const float* __restrict__ x, ushort* __restrict__ y, int total4) {
    int i = blockIdx.x * 256 + threadIdx.x;
    if (i < total4) {
        float4 v = ((const float4*)x)[i];
        ushort4 o;
        o.x = f2b(v.x); o.y = f2b(v.y); o.z = f2b(v.z); o.w = f2b(v.w);
        ((ushort4*)y)[i] = o;
    }
}

// wT[col][k] (k=0..255: Ws rows then Wn rows), bf16
__global__ void k_castw(const float* __restrict__ Ws, const float* __restrict__ Wn,
                        ushort* __restrict__ wT) {
    int i = blockIdx.x * 256 + threadIdx.x;   // 32768
    int c = i >> 8, k = i & 255;
    float v = (k < 128) ? Ws[k * 128 + c] : Wn[(k - 128) * 128 + c];
    wT[c * 256 + k] = f2b(v);
}

// ---------------- bf16 neighbor-mean gather: wave per node, bf16 out --------

__global__ __launch_bounds__(256) void k_aggb(
    const ushort* __restrict__ fb, const int* __restrict__ rowptr,
    const int* __restrict__ csr, const float* __restrict__ invdeg,
    ushort* __restrict__ outb, int N) {
    int lane = threadIdx.x & 63;
    int n = blockIdx.x * 4 + (threadIdx.x >> 6);
    if (n >= N) return;
    int r0 = rowptr[n], r1 = rowptr[n + 1];
    int ej = lane >> 4;      // 0..3
    int cg = lane & 15;      // cols cg*8 .. cg*8+7

    float acc[8];
#pragma unroll
    for (int i = 0; i < 8; i++) acc[i] = 0.f;

    int e = r0 + ej;
    for (; e + 4 < r1; e += 8) {
        int s0 = csr[e];
        int s1 = csr[e + 4];
        uint4 v0 = *(const uint4*)(fb + (size_t)s0 * D + cg * 8);
        uint4 v1 = *(const uint4*)(fb + (size_t)s1 * D + cg * 8);
        acc[0] += __uint_as_float(v0.x << 16);
        acc[1] += __uint_as_float(v0.x & 0xffff0000u);
        acc[2] += __uint_as_float(v0.y << 16);
        acc[3] += __uint_as_float(v0.y & 0xffff0000u);
        acc[4] += __uint_as_float(v0.z << 16);
        acc[5] += __uint_as_float(v0.z & 0xffff0000u);
        acc[6] += __uint_as_float(v0.w << 16);
        acc[7] += __uint_as_float(v0.w & 0xffff0000u);
        acc[0] += __uint_as_float(v1.x << 16);
        acc[1] += __uint_as_float(v1.x & 0xffff0000u);
        acc[2] += __uint_as_float(v1.y << 16);
        acc[3] += __uint_as_float(v1.y & 0xffff0000u);
        acc[4] += __uint_as_float(v1.z << 16);
        acc[5] += __uint_as_float(v1.z & 0xffff0000u);
        acc[6] += __uint_as_float(v1.w << 16);
        acc[7] += __uint_as_float(v1.w & 0xffff0000u);
    }
    for (; e < r1; e += 4) {
        int s = csr[e];
        uint4 v = *(const uint4*)(fb + (size_t)s * D + cg * 8);
        acc[0] += __uint_as_float(v.x << 16);
        acc[1] += __uint_as_float(v.x & 0xffff0000u);
        acc[2] += __uint_as_float(v.y << 16);
        acc[3] += __uint_as_float(v.y & 0xffff0000u);
        acc[4] += __uint_as_float(v.z << 16);
        acc[5] += __uint_as_float(v.z & 0xffff0000u);
        acc[6] += __uint_as_float(v.w << 16);
        acc[7] += __uint_as_float(v.w & 0xffff0000u);
    }
#pragma unroll
    for (int i = 0; i < 8; i++) {
        acc[i] += __shfl_xor(acc[i], 16);
        acc[i] += __shfl_xor(acc[i], 32);
    }
    if (ej == 0) {
        float id = invdeg[n];
        uint4 o;
        o.x = (uint)f2b(acc[0] * id) | ((uint)f2b(acc[1] * id) << 16);
        o.y = (uint)f2b(acc[2] * id) | ((uint)f2b(acc[3] * id) << 16);
        o.z = (uint)f2b(acc[4] * id) | ((uint)f2b(acc[5] * id) << 16);
        o.w = (uint)f2b(acc[6] * id) | ((uint)f2b(acc[7] * id) << 16);
        *(uint4*)(outb + (size_t)n * D + cg * 8) = o;
    }
}

// ---------------- layer-1 GEMM via MFMA (bf16 in, bf16 out) ----------------
// x1b = bf16(relu([hb|nbb] @ wT^T + b)), K=256. Block: 128 rows x 128 cols,
// 4 waves; wave w = rows [w*32,w*32+32) x all 128 cols = 2x8 16x16 tiles.
// Layouts (m89/m120-verified): A[m=lane&15][k=quad*8+j]; B[k=quad*8+j][n=lane&15]
// from col-major LDS; C/D col=lane&15, row=quad*4+reg.

__global__ __launch_bounds__(256, 2) void k_mm1m(
    const ushort* __restrict__ hb, const ushort* __restrict__ nbb,
    const ushort* __restrict__ wT, const float* __restrict__ b,
    ushort* __restrict__ x1b, int N) {
    __shared__ __align__(16) ushort As[128 * LDA];
    __shared__ __align__(16) ushort Bs[128 * LDA];
    int t    = threadIdx.x;
    int w    = t >> 6;
    int lane = t & 63;
    int m    = lane & 15;
    int quad = lane >> 4;
    int n0   = blockIdx.x * 128;

    f32x4 acc[2][8];
#pragma unroll
    for (int rt = 0; rt < 2; rt++)
#pragma unroll
        for (int ct = 0; ct < 8; ct++) acc[rt][ct] = (f32x4){0.f, 0.f, 0.f, 0.f};

#pragma unroll 1
    for (int kc = 0; kc < 8; kc++) {
        int k0 = kc * 32;
        const ushort* __restrict__ A = (k0 < 128) ? hb : nbb;
        int ka = k0 & 127;
        __syncthreads();
        // stage A: 128 rows x 32 k (uint4 = 8 bf16), 2 per thread
#pragma unroll
        for (int i = 0; i < 2; i++) {
            int linear = i * 256 + t;       // 0..511
            int row = linear >> 2;
            int q   = linear & 3;
            int nn = n0 + row;
            uint4 v = make_uint4(0u, 0u, 0u, 0u);
            if (nn < N) v = *(const uint4*)(A + (size_t)nn * D + ka + q * 8);
            *(uint4*)(&As[row * LDA + q * 8]) = v;
        }
        // stage B: 128 cols x 32 k from wT[col][256]
#pragma unroll
        for (int i = 0; i < 2; i++) {
            int linear = i * 256 + t;
            int col = linear >> 2;
            int q   = linear & 3;
            uint4 v = *(const uint4*)(wT + (size_t)col * 256 + k0 + q * 8);
            *(uint4*)(&Bs[col * LDA + q * 8]) = v;
        }
        __syncthreads();
        short8 af[2], bf[8];
#pragma unroll
        for (int rt = 0; rt < 2; rt++)
            af[rt] = *(const short8*)(&As[(w * 32 + rt * 16 + m) * LDA + quad * 8]);
#pragma unroll
        for (int ct = 0; ct < 8; ct++)
            bf[ct] = *(const short8*)(&Bs[(ct * 16 + m) * LDA + quad * 8]);
#pragma unroll
        for (int rt = 0; rt < 2; rt++)
#pragma unroll
            for (int ct = 0; ct < 8; ct++)
                acc[rt][ct] = __builtin_amdgcn_mfma_f32_16x16x32_bf16(
                    af[rt], bf[ct], acc[rt][ct], 0, 0, 0);
    }
    // epilogue: bias + relu + bf16 store
#pragma unroll
    for (int ct = 0; ct < 8; ct++) {
        float bias = b[ct * 16 + m];
#pragma unroll
        for (int rt = 0; rt < 2; rt++) {
#pragma unroll
            for (int r = 0; r < 4; r++) {
                int n = n0 + w * 32 + rt * 16 + quad * 4 + r;
                if (n < N)
                    x1b[(size_t)n * D + ct * 16 + m] =
                        f2b(fmaxf(acc[rt][ct][r] + bias, 0.f));
            }
        }
    }
}

// ---------------- per-graph sums (graph_ids sorted; both inputs bf16) -------

__global__ __launch_bounds__(128) void k_gsum(
    const ushort* __restrict__ x1b, const ushort* __restrict__ n2b,
    const int* __restrict__ gid, float* __restrict__ S1,
    float* __restrict__ S2, int N) {
    int t = threadIdx.x;
    int cg = t & 15;       // cols cg*8 .. +7
    int rl = t >> 4;       // 0..7
    int base = blockIdx.x * GS_ROWS;
    float a1[8], a2[8];
#pragma unroll
    for (int i = 0; i < 8; i++) { a1[i] = 0.f; a2[i] = 0.f; }
    int cur = -1;
    for (int j = rl; j < GS_ROWS; j += 8) {
        int n = base + j;
        if (n >= N) break;
        int g = gid[n];
        if (g != cur) {
            if (cur >= 0) {
#pragma unroll
                for (int i = 0; i < 8; i++) {
                    atomicAdd(&S1[cur * D + cg * 8 + i], a1[i]);
                    atomicAdd(&S2[cur * D + cg * 8 + i], a2[i]);
                }
            }
#pragma unroll
            for (int i = 0; i < 8; i++) { a1[i] = 0.f; a2[i] = 0.f; }
            cur = g;
        }
        uint4 v = *(const uint4*)(x1b + (size_t)n * D + cg * 8);
        a1[0] += __uint_as_float(v.x << 16);
        a1[1] += __uint_as_float(v.x & 0xffff0000u);
        a1[2] += __uint_as_float(v.y << 16);
        a1[3] += __uint_as_float(v.y & 0xffff0000u);
        a1[4] += __uint_as_float(v.z << 16);
        a1[5] += __uint_as_float(v.z & 0xffff0000u);
        a1[6] += __uint_as_float(v.w << 16);
        a1[7] += __uint_as_float(v.w & 0xffff0000u);
        uint4 u = *(const uint4*)(n2b + (size_t)n * D + cg * 8);
        a2[0] += __uint_as_float(u.x << 16);
        a2[1] += __uint_as_float(u.x & 0xffff0000u);
        a2[2] += __uint_as_float(u.y << 16);
        a2[3] += __uint_as_float(u.y & 0xffff0000u);
        a2[4] += __uint_as_float(u.z << 16);
        a2[5] += __uint_as_float(u.z & 0xffff0000u);
        a2[6] += __uint_as_float(u.w << 16);
        a2[7] += __uint_as_float(u.w & 0xffff0000u);
    }
    if (cur >= 0) {
#pragma unroll
        for (int i = 0; i < 8; i++) {
            atomicAdd(&S1[cur * D + cg * 8 + i], a1[i]);
            atomicAdd(&S2[cur * D + cg * 8 + i], a2[i]);
        }
    }
}

// ---------------- final: hg = (S1@W2s + S2@W2n)/cnt + b2 ; out = hg@Wc + bc ----

__global__ void k_final(const float* __restrict__ S1, const float* __restrict__ S2,
                        const int* __restrict__ gcnt, const float* __restrict__ W2s,
                        const float* __restrict__ W2n, const float* __restrict__ b2,
                        const float* __restrict__ Wc, const float* __restrict__ bc,
                        float* __restrict__ out) {
    __shared__ float s1[D], s2[D], hg[D];
    int g = blockIdx.x, c = threadIdx.x;
    s1[c] = S1[g * D + c];
    s2[c] = S2[g * D + c];
    __syncthreads();
    float acc = 0.f;
#pragma unroll 8
    for (int k = 0; k < D; k++) {
        acc = fmaf(s1[k], W2s[k * D + c], acc);
        acc = fmaf(s2[k], W2n[k * D + c], acc);
    }
    int cnt = gcnt[g];
    hg[c] = (cnt > 0) ? (acc / (float)cnt + b2[c]) : 0.f;
    __syncthreads();
    if (c < N_CLS) {
        float o = bc[c];
        for (int k = 0; k < D; k++) o = fmaf(hg[k], Wc[k * N_CLS + c], o);
        out[g * N_CLS + c] = o;
    }
}

// ---------------- launch ----------------

extern "C" void kernel_launch(void* const* d_in, const int* in_sizes, int n_in,
                              void* d_out, int out_size, void* d_ws, size_t ws_size,
                              hipStream_t stream) {
    const float* h   = (const float*)d_in[0];
    const int*   src = (const int*)d_in[1];
    const int*   dst = (const int*)d_in[2];
    const int*   gid = (const int*)d_in[3];
    const float* W1s = (const float*)d_in[5];
    const float* W1n = (const float*)d_in[6];
    const float* b1  = (const float*)d_in[7];
    const float* W2s = (const float*)d_in[8];
    const float* W2n = (const float*)d_in[9];
    const float* b2  = (const float*)d_in[10];
    const float* Wc  = (const float*)d_in[11];
    const float* bc  = (const float*)d_in[12];
    float* out = (float*)d_out;

    const int N = in_sizes[0] / D;  // 100000
    const int E = in_sizes[1];      // 1600000

    char* w = (char*)d_ws;
    size_t off = 0;
    auto alloc = [&](size_t elems) -> void* {   // elems are 4-byte units
        void* p = w + off;
        off += elems * 4;
        return p;
    };
    // zero-initialized region first (one memset)
    float* S1     = (float*)alloc((size_t)N_GRAPHS * D);
    float* S2     = (float*)alloc((size_t)N_GRAPHS * D);
    int*   deg    = (int*)alloc(N);
    int*   cursor = (int*)alloc(N);
    int*   gcnt   = (int*)alloc(64);
    size_t zero_bytes = off;
    int*   rowptr = (int*)alloc(N + 4);
    float* invdeg = (float*)alloc(N);
    int*   bsum   = (int*)alloc(128);
    int*   boff   = (int*)alloc(128);
    int*   csr    = (int*)alloc(E);
    ushort* fb    = (ushort*)alloc((size_t)N * 64);   // bf16 [N,128] h
    ushort* nbb   = (ushort*)alloc((size_t)N * 64);   // bf16 [N,128] neigh1 / neigh2
    ushort* x1b   = (ushort*)alloc((size_t)N * 64);   // bf16 [N,128] x1
    ushort* wT    = (ushort*)alloc(16384);            // bf16 [128 cols][256 k]
    (void)ws_size;

    hipMemsetAsync(d_ws, 0, zero_bytes, stream);

    int eb  = (E + 255) / 256;
    int nbk = (N + 255) / 256;
    int nch = (N + 1023) / 1024;
    int t4  = N * 32;  // float4 count of [N,128] f32

    k_cast<<<(t4 + 255) / 256, 256, 0, stream>>>(h, fb, t4);
    k_castw<<<128, 256, 0, stream>>>(W1s, W1n, wT);
    k_deg<<<eb, 256, 0, stream>>>(dst, deg, E);
    k_scan1<<<nch, 1024, 0, stream>>>(deg, rowptr, bsum, N);
    k_scan2<<<1, 64, 0, stream>>>(bsum, boff, nch);
    k_scan3<<<nbk, 256, 0, stream>>>(deg, rowptr, boff, invdeg, N);
    k_scatter<<<eb, 256, 0, stream>>>(src, dst, rowptr, cursor, csr, E);
    k_hist<<<nbk, 256, 0, stream>>>(gid, gcnt, N);
    k_aggb<<<(N + 3) / 4, 256, 0, stream>>>(fb, rowptr, csr, invdeg, nbb, N);
    k_mm1m<<<(N + 127) / 128, 256, 0, stream>>>(fb, nbb, wT, b1, x1b, N);
    k_aggb<<<(N + 3) / 4, 256, 0, stream>>>(x1b, rowptr, csr, invdeg, nbb, N);
    k_gsum<<<(N + GS_ROWS - 1) / GS_ROWS, 128, 0, stream>>>(x1b, nbb, gid, S1, S2, N);
    k_final<<<N_GRAPHS, 128, 0, stream>>>(S1, S2, gcnt, W2s, W2n, b2, Wc, bc, out);
}

// Round 7
// 475.290 us; speedup vs baseline: 2.7668x; 1.2478x over previous
//
#include <hip/hip_runtime.h>

#define D        128
#define N_GRAPHS 64
#define N_CLS    16
#define LDA      40   // LDS row stride in bf16 elems (80 B: 16B-aligned, 2-way banks = free)

typedef unsigned int  uint;
typedef unsigned short ushort;
typedef __attribute__((ext_vector_type(8))) short short8;
typedef __attribute__((ext_vector_type(4))) float f32x4;

__device__ inline ushort f2b(float f) {   // f32 -> bf16 RNE
    uint u = __float_as_uint(f);
    u += 0x7fffu + ((u >> 16) & 1u);
    return (ushort)(u >> 16);
}

// ---------------- CSR build ----------------
// deg count + slot capture: the atomic already RMWs the sector; slot write is
// coalesced. Removes all atomics from k_scatter.

__global__ void k_degslot(const int* __restrict__ dst, int* __restrict__ deg,
                          int* __restrict__ slot, int E) {
    int e = blockIdx.x * 256 + threadIdx.x;
    if (e < E) slot[e] = atomicAdd(&deg[dst[e]], 1);
}

__global__ void k_scan1(const int* __restrict__ deg, int* __restrict__ rowptr,
                        int* __restrict__ bsum, int N) {
    __shared__ int sh[1024];
    int t = threadIdx.x;
    int i = blockIdx.x * 1024 + t;
    int v = (i < N) ? deg[i] : 0;
    sh[t] = v;
    __syncthreads();
    for (int off = 1; off < 1024; off <<= 1) {
        int tmp = (t >= off) ? sh[t - off] : 0;
        __syncthreads();
        sh[t] += tmp;
        __syncthreads();
    }
    if (i < N) rowptr[i + 1] = sh[t];
    if (t == 1023) bsum[blockIdx.x] = sh[1023];
}

__global__ void k_scan2(const int* __restrict__ bsum, int* __restrict__ boff, int nch) {
    if (threadIdx.x == 0 && blockIdx.x == 0) {
        int run = 0;
        for (int j = 0; j < nch; j++) { boff[j] = run; run += bsum[j]; }
    }
}

__global__ void k_scan3(const int* __restrict__ deg, int* __restrict__ rowptr,
                        const int* __restrict__ boff, float* __restrict__ invdeg, int N) {
    int i = blockIdx.x * 256 + threadIdx.x;
    if (i < N) {
        rowptr[i + 1] += boff[i >> 10];
        int d = deg[i];
        invdeg[i] = 1.0f / (float)(d > 1 ? d : 1);
        if (i == 0) rowptr[0] = 0;
    }
}

// atomic-free scatter: position known from slot[e]
__global__ void k_scatter(const int* __restrict__ src, const int* __restrict__ dst,
                          const int* __restrict__ rowptr, const int* __restrict__ slot,
                          int* __restrict__ csr, int E) {
    int e = blockIdx.x * 256 + threadIdx.x;
    if (e < E) csr[rowptr[dst[e]] + slot[e]] = src[e];
}

// graph boundaries from sorted gid: gstart[g] = lower_bound(gid, g)
__global__ void k_gbound(const int* __restrict__ gid, int* __restrict__ gstart, int N) {
    int g = threadIdx.x;
    if (g > N_GRAPHS) return;
    int lo = 0, hi = N;
    while (lo < hi) {
        int mid = (lo + hi) >> 1;
        if (gid[mid] < g) lo = mid + 1; else hi = mid;
    }
    gstart[g] = lo;
}

// ---------------- casts ----------------

__global__ void k_cast(const float* __restrict__ x, ushort* __restrict__ y, int total4) {
    int i = blockIdx.x * 256 + threadIdx.x;
    if (i < total4) {
        float4 v = ((const float4*)x)[i];
        ushort4 o;
        o.x = f2b(v.x); o.y = f2b(v.y); o.z = f2b(v.z); o.w = f2b(v.w);
        ((ushort4*)y)[i] = o;
    }
}

// wT[col][k] (k=0..255: Ws rows then Wn rows), bf16
__global__ void k_castw(const float* __restrict__ Ws, const float* __restrict__ Wn,
                        ushort* __restrict__ wT) {
    int i = blockIdx.x * 256 + threadIdx.x;   // 32768
    int c = i >> 8, k = i & 255;
    float v = (k < 128) ? Ws[k * 128 + c] : Wn[(k - 128) * 128 + c];
    wT[c * 256 + k] = f2b(v);
}

// ---------------- bf16 neighbor-mean gather: wave per node, bf16 out --------

__global__ __launch_bounds__(256) void k_aggb(
    const ushort* __restrict__ fb, const int* __restrict__ rowptr,
    const int* __restrict__ csr, const float* __restrict__ invdeg,
    ushort* __restrict__ outb, int N) {
    int lane = threadIdx.x & 63;
    int n = blockIdx.x * 4 + (threadIdx.x >> 6);
    if (n >= N) return;
    int r0 = rowptr[n], r1 = rowptr[n + 1];
    int ej = lane >> 4;      // 0..3
    int cg = lane & 15;      // cols cg*8 .. cg*8+7

    float acc[8];
#pragma unroll
    for (int i = 0; i < 8; i++) acc[i] = 0.f;

    int e = r0 + ej;
    for (; e + 4 < r1; e += 8) {
        int s0 = csr[e];
        int s1 = csr[e + 4];
        uint4 v0 = *(const uint4*)(fb + (size_t)s0 * D + cg * 8);
        uint4 v1 = *(const uint4*)(fb + (size_t)s1 * D + cg * 8);
        acc[0] += __uint_as_float(v0.x << 16);
        acc[1] += __uint_as_float(v0.x & 0xffff0000u);
        acc[2] += __uint_as_float(v0.y << 16);
        acc[3] += __uint_as_float(v0.y & 0xffff0000u);
        acc[4] += __uint_as_float(v0.z << 16);
        acc[5] += __uint_as_float(v0.z & 0xffff0000u);
        acc[6] += __uint_as_float(v0.w << 16);
        acc[7] += __uint_as_float(v0.w & 0xffff0000u);
        acc[0] += __uint_as_float(v1.x << 16);
        acc[1] += __uint_as_float(v1.x & 0xffff0000u);
        acc[2] += __uint_as_float(v1.y << 16);
        acc[3] += __uint_as_float(v1.y & 0xffff0000u);
        acc[4] += __uint_as_float(v1.z << 16);
        acc[5] += __uint_as_float(v1.z & 0xffff0000u);
        acc[6] += __uint_as_float(v1.w << 16);
        acc[7] += __uint_as_float(v1.w & 0xffff0000u);
    }
    for (; e < r1; e += 4) {
        int s = csr[e];
        uint4 v = *(const uint4*)(fb + (size_t)s * D + cg * 8);
        acc[0] += __uint_as_float(v.x << 16);
        acc[1] += __uint_as_float(v.x & 0xffff0000u);
        acc[2] += __uint_as_float(v.y << 16);
        acc[3] += __uint_as_float(v.y & 0xffff0000u);
        acc[4] += __uint_as_float(v.z << 16);
        acc[5] += __uint_as_float(v.z & 0xffff0000u);
        acc[6] += __uint_as_float(v.w << 16);
        acc[7] += __uint_as_float(v.w & 0xffff0000u);
    }
#pragma unroll
    for (int i = 0; i < 8; i++) {
        acc[i] += __shfl_xor(acc[i], 16);
        acc[i] += __shfl_xor(acc[i], 32);
    }
    if (ej == 0) {
        float id = invdeg[n];
        uint4 o;
        o.x = (uint)f2b(acc[0] * id) | ((uint)f2b(acc[1] * id) << 16);
        o.y = (uint)f2b(acc[2] * id) | ((uint)f2b(acc[3] * id) << 16);
        o.z = (uint)f2b(acc[4] * id) | ((uint)f2b(acc[5] * id) << 16);
        o.w = (uint)f2b(acc[6] * id) | ((uint)f2b(acc[7] * id) << 16);
        *(uint4*)(outb + (size_t)n * D + cg * 8) = o;
    }
}

// ---------------- layer-1 GEMM via MFMA (bf16 in, bf16 out) ----------------

__global__ __launch_bounds__(256, 2) void k_mm1m(
    const ushort* __restrict__ hb, const ushort* __restrict__ nbb,
    const ushort* __restrict__ wT, const float* __restrict__ b,
    ushort* __restrict__ x1b, int N) {
    __shared__ __align__(16) ushort As[128 * LDA];
    __shared__ __align__(16) ushort Bs[128 * LDA];
    int t    = threadIdx.x;
    int w    = t >> 6;
    int lane = t & 63;
    int m    = lane & 15;
    int quad = lane >> 4;
    int n0   = blockIdx.x * 128;

    f32x4 acc[2][8];
#pragma unroll
    for (int rt = 0; rt < 2; rt++)
#pragma unroll
        for (int ct = 0; ct < 8; ct++) acc[rt][ct] = (f32x4){0.f, 0.f, 0.f, 0.f};

#pragma unroll 1
    for (int kc = 0; kc < 8; kc++) {
        int k0 = kc * 32;
        const ushort* __restrict__ A = (k0 < 128) ? hb : nbb;
        int ka = k0 & 127;
        __syncthreads();
#pragma unroll
        for (int i = 0; i < 2; i++) {
            int linear = i * 256 + t;       // 0..511
            int row = linear >> 2;
            int q   = linear & 3;
            int nn = n0 + row;
            uint4 v = make_uint4(0u, 0u, 0u, 0u);
            if (nn < N) v = *(const uint4*)(A + (size_t)nn * D + ka + q * 8);
            *(uint4*)(&As[row * LDA + q * 8]) = v;
        }
#pragma unroll
        for (int i = 0; i < 2; i++) {
            int linear = i * 256 + t;
            int col = linear >> 2;
            int q   = linear & 3;
            uint4 v = *(const uint4*)(wT + (size_t)col * 256 + k0 + q * 8);
            *(uint4*)(&Bs[col * LDA + q * 8]) = v;
        }
        __syncthreads();
        short8 af[2], bf[8];
#pragma unroll
        for (int rt = 0; rt < 2; rt++)
            af[rt] = *(const short8*)(&As[(w * 32 + rt * 16 + m) * LDA + quad * 8]);
#pragma unroll
        for (int ct = 0; ct < 8; ct++)
            bf[ct] = *(const short8*)(&Bs[(ct * 16 + m) * LDA + quad * 8]);
#pragma unroll
        for (int rt = 0; rt < 2; rt++)
#pragma unroll
            for (int ct = 0; ct < 8; ct++)
                acc[rt][ct] = __builtin_amdgcn_mfma_f32_16x16x32_bf16(
                    af[rt], bf[ct], acc[rt][ct], 0, 0, 0);
    }
#pragma unroll
    for (int ct = 0; ct < 8; ct++) {
        float bias = b[ct * 16 + m];
#pragma unroll
        for (int rt = 0; rt < 2; rt++) {
#pragma unroll
            for (int r = 0; r < 4; r++) {
                int n = n0 + w * 32 + rt * 16 + quad * 4 + r;
                if (n < N)
                    x1b[(size_t)n * D + ct * 16 + m] =
                        f2b(fmaxf(acc[rt][ct][r] + bias, 0.f));
            }
        }
    }
}

// ---------------- per-graph sums: contention-free via gstart ----------------
// grid = 64 graphs x 8 chunks; block 256 = (mat 2) x (row-parity 2) x (col-pair 64).
// Register accumulate over the contiguous row range, single flush.

__global__ __launch_bounds__(256) void k_gsum(
    const ushort* __restrict__ x1b, const ushort* __restrict__ n2b,
    const int* __restrict__ gstart, float* __restrict__ S1,
    float* __restrict__ S2) {
    int g  = blockIdx.x >> 3;
    int ch = blockIdx.x & 7;
    int r0 = gstart[g], r1 = gstart[g + 1];
    int len = r1 - r0;
    if (len <= 0) return;
    int L = (len + 7) >> 3;
    int a = r0 + ch * L;
    int bnd = min(a + L, r1);
    if (a >= bnd) return;

    int tid = threadIdx.x;
    int mat = tid >> 7;          // 0: x1b->S1, 1: n2b->S2
    int rp  = (tid >> 6) & 1;    // row parity
    int cp  = tid & 63;          // col pair (2 bf16 per uint)
    const ushort* __restrict__ M = mat ? n2b : x1b;
    float ax = 0.f, ay = 0.f;
    for (int n = a + rp; n < bnd; n += 2) {
        uint v = *(const uint*)(M + (size_t)n * D + cp * 2);
        ax += __uint_as_float(v << 16);
        ay += __uint_as_float(v & 0xffff0000u);
    }
    float* __restrict__ S = mat ? S2 : S1;
    atomicAdd(&S[g * D + cp * 2], ax);
    atomicAdd(&S[g * D + cp * 2 + 1], ay);
}

// ---------------- final: hg = (S1@W2s + S2@W2n)/cnt + b2 ; out = hg@Wc + bc ----

__global__ void k_final(const float* __restrict__ S1, const float* __restrict__ S2,
                        const int* __restrict__ gstart, const float* __restrict__ W2s,
                        const float* __restrict__ W2n, const float* __restrict__ b2,
                        const float* __restrict__ Wc, const float* __restrict__ bc,
                        float* __restrict__ out) {
    __shared__ float s1[D], s2[D], hg[D];
    int g = blockIdx.x, c = threadIdx.x;
    s1[c] = S1[g * D + c];
    s2[c] = S2[g * D + c];
    __syncthreads();
    float acc = 0.f;
#pragma unroll 8
    for (int k = 0; k < D; k++) {
        acc = fmaf(s1[k], W2s[k * D + c], acc);
        acc = fmaf(s2[k], W2n[k * D + c], acc);
    }
    int cnt = gstart[g + 1] - gstart[g];
    hg[c] = (cnt > 0) ? (acc / (float)cnt + b2[c]) : 0.f;
    __syncthreads();
    if (c < N_CLS) {
        float o = bc[c];
        for (int k = 0; k < D; k++) o = fmaf(hg[k], Wc[k * N_CLS + c], o);
        out[g * N_CLS + c] = o;
    }
}

// ---------------- launch ----------------

extern "C" void kernel_launch(void* const* d_in, const int* in_sizes, int n_in,
                              void* d_out, int out_size, void* d_ws, size_t ws_size,
                              hipStream_t stream) {
    const float* h   = (const float*)d_in[0];
    const int*   src = (const int*)d_in[1];
    const int*   dst = (const int*)d_in[2];
    const int*   gid = (const int*)d_in[3];
    const float* W1s = (const float*)d_in[5];
    const float* W1n = (const float*)d_in[6];
    const float* b1  = (const float*)d_in[7];
    const float* W2s = (const float*)d_in[8];
    const float* W2n = (const float*)d_in[9];
    const float* b2  = (const float*)d_in[10];
    const float* Wc  = (const float*)d_in[11];
    const float* bc  = (const float*)d_in[12];
    float* out = (float*)d_out;

    const int N = in_sizes[0] / D;  // 100000
    const int E = in_sizes[1];      // 1600000

    char* w = (char*)d_ws;
    size_t off = 0;
    auto alloc = [&](size_t elems) -> void* {   // elems are 4-byte units
        void* p = w + off;
        off += elems * 4;
        return p;
    };
    // zero-initialized region first (one memset)
    float* S1     = (float*)alloc((size_t)N_GRAPHS * D);
    float* S2     = (float*)alloc((size_t)N_GRAPHS * D);
    int*   deg    = (int*)alloc(N);
    size_t zero_bytes = off;
    int*   rowptr = (int*)alloc(N + 4);
    float* invdeg = (float*)alloc(N);
    int*   bsum   = (int*)alloc(128);
    int*   boff   = (int*)alloc(128);
    int*   gstart = (int*)alloc(128);
    int*   slot   = (int*)alloc(E);
    int*   csr    = (int*)alloc(E);
    ushort* fb    = (ushort*)alloc((size_t)N * 64);   // bf16 [N,128] h
    ushort* nbb   = (ushort*)alloc((size_t)N * 64);   // bf16 [N,128] neigh1 / neigh2
    ushort* x1b   = (ushort*)alloc((size_t)N * 64);   // bf16 [N,128] x1
    ushort* wT    = (ushort*)alloc(16384);            // bf16 [128 cols][256 k]
    (void)ws_size;

    hipMemsetAsync(d_ws, 0, zero_bytes, stream);

    int eb  = (E + 255) / 256;
    int nbk = (N + 255) / 256;
    int nch = (N + 1023) / 1024;
    int t4  = N * 32;  // float4 count of [N,128] f32

    k_cast<<<(t4 + 255) / 256, 256, 0, stream>>>(h, fb, t4);
    k_castw<<<128, 256, 0, stream>>>(W1s, W1n, wT);
    k_degslot<<<eb, 256, 0, stream>>>(dst, deg, slot, E);
    k_scan1<<<nch, 1024, 0, stream>>>(deg, rowptr, bsum, N);
    k_scan2<<<1, 64, 0, stream>>>(bsum, boff, nch);
    k_scan3<<<nbk, 256, 0, stream>>>(deg, rowptr, boff, invdeg, N);
    k_scatter<<<eb, 256, 0, stream>>>(src, dst, rowptr, slot, csr, E);
    k_gbound<<<1, 128, 0, stream>>>(gid, gstart, N);
    k_aggb<<<(N + 3) / 4, 256, 0, stream>>>(fb, rowptr, csr, invdeg, nbb, N);
    k_mm1m<<<(N + 127) / 128, 256, 0, stream>>>(fb, nbb, wT, b1, x1b, N);
    k_aggb<<<(N + 3) / 4, 256, 0, stream>>>(x1b, rowptr, csr, invdeg, nbb, N);
    k_gsum<<<N_GRAPHS * 8, 256, 0, stream>>>(x1b, nbb, gstart, S1, S2);
    k_final<<<N_GRAPHS, 128, 0, stream>>>(S1, S2, gstart, W2s, W2n, b2, Wc, bc, out);
}